// Round 6
// baseline (612.856 us; speedup 1.0000x reference)
//
#include <hip/hip_runtime.h>

// GateRecurrent2dnoind: left-to-right SPN scan over W, 3-pt stencil along H.
// [N=8, C=64, H=256, W=256] fp32.
//
// One single-wave block per (n,c) plane. Lane l owns rows 4l..4l+3 ->
// vertical exchange = 2 shuffles/step, zero barriers.
// R6: HC=4-col half-tiles, 4 distinct buffers (64 KB LDS -> 2 blocks/CU, all
// 512 waves resident), prefetch distance 3 halves into buffer (h+3)&3 (the
// buffer consumed at h-1 -> no same-buffer hazard, NO lgkm serialization,
// restoring R4's free pipelining at R5's occupancy). Counted vmcnt ledger
// includes the store stream (16 stores after every 4th half).
// Swizzle: row g stored at slot g ^ ((g>>3)&7) (involution); staging lane j
// loads row j ^ ((j>>3)&7); scan ds_read_b128 slot (4l+r) ^ ((l>>1)&7) ->
// conflict-free.

constexpr int H  = 256;
constexpr int W  = 256;
constexpr int HC = 4;           // cols per half-tile

#define F4C(v, j) ((&(v).x)[j])
#define WAITV(N) asm volatile("s_waitcnt vmcnt(" #N ")" ::: "memory")

typedef const __attribute__((address_space(1))) void* gas_ptr;
typedef __attribute__((address_space(3))) void* las_ptr;

__device__ __forceinline__ void gl16(const float* g, float4* l) {
    __builtin_amdgcn_global_load_lds((gas_ptr)(const void*)g, (las_ptr)(void*)l,
                                     16, 0, 0);
}

struct Ptrs { const float *i0, *i1, *i2, *i3; };   // pre-offset by jp*W

// issue the 16 global->LDS loads of half-tile h into buf[4 arrays][256 slots]
__device__ __forceinline__
void issue_half(const Ptrs& P, float4 (*buf)[256], int h)
{
    const int base = h * HC;
#pragma unroll
    for (int i = 0; i < 4; ++i) {
        const int go = base + i * (64 * W);    // rows 64i..64i+63 (swizzled)
        gl16(P.i0 + go, &buf[0][i * 64]);
        gl16(P.i1 + go, &buf[1][i * 64]);
        gl16(P.i2 + go, &buf[2][i * 64]);
        gl16(P.i3 + go, &buf[3][i * 64]);
    }
}

// one half-tile: issue prefetch (distinct buffer, no hazard) -> 16 ds_read_b128
// -> 4 sequential scan steps. S = sub-half index (o[] column group).
template<int S>
__device__ __forceinline__
void iter_body(const float4 (*A)[256], const Ptrs& P, float4 (*nextbuf)[256],
               int hnext, bool do_issue, int l, int lm,
               float& h0, float& h1, float& h2, float& h3, float4 o[4][4])
{
    if (do_issue) issue_half(P, nextbuf, hnext);

    float4 q[4][4];                       // [row r][array a]
#pragma unroll
    for (int r = 0; r < 4; ++r) {
        const int sl = (4 * l + r) ^ lm;
#pragma unroll
        for (int a = 0; a < 4; ++a)
            q[r][a] = A[a][sl];
    }

#pragma unroll
    for (int j = 0; j < 4; ++j) {
        float up = __shfl_up(h3, 1);            // lane-1's row 4l-1
        float dn = __shfl_down(h0, 1);          // lane+1's row 4l+4
        if (l == 0)  up = 0.f;
        if (l == 63) dn = 0.f;

        const float x0 = F4C(q[0][0], j), a10 = F4C(q[0][1], j),
                    a20 = F4C(q[0][2], j), a30 = F4C(q[0][3], j);
        const float x1 = F4C(q[1][0], j), a11 = F4C(q[1][1], j),
                    a21 = F4C(q[1][2], j), a31 = F4C(q[1][3], j);
        const float x2 = F4C(q[2][0], j), a12 = F4C(q[2][1], j),
                    a22 = F4C(q[2][2], j), a32 = F4C(q[2][3], j);
        const float x3 = F4C(q[3][0], j), a13 = F4C(q[3][1], j),
                    a23 = F4C(q[3][2], j), a33 = F4C(q[3][3], j);

        const float n0 = fmaf(a30, h1, fmaf(a20, h0,
                         fmaf(a10, up, x0 * (1.f - a10 - a20 - a30))));
        const float n1 = fmaf(a31, h2, fmaf(a21, h1,
                         fmaf(a11, h0, x1 * (1.f - a11 - a21 - a31))));
        const float n2 = fmaf(a32, h3, fmaf(a22, h2,
                         fmaf(a12, h1, x2 * (1.f - a12 - a22 - a32))));
        const float n3 = fmaf(a33, dn, fmaf(a23, h3,
                         fmaf(a13, h2, x3 * (1.f - a13 - a23 - a33))));

        h0 = n0; h1 = n1; h2 = n2; h3 = n3;
        F4C(o[0][S], j) = n0;
        F4C(o[1][S], j) = n1;
        F4C(o[2][S], j) = n2;
        F4C(o[3][S], j) = n3;
    }
}

__global__ __launch_bounds__(64)
void spn_wave(const float* __restrict__ X,  const float* __restrict__ G1,
              const float* __restrict__ G2, const float* __restrict__ G3,
              float* __restrict__ O)
{
    __shared__ float4 lds4[4][4][256];   // [buf][array][slot] = 64 KiB

    const int l  = threadIdx.x;          // 0..63
    const int lm = (l >> 1) & 7;         // read-slot XOR key
    const size_t pb = (size_t)blockIdx.x * (size_t)(H * W);

    // staging: lane j loads row jp = j ^ ((j>>3)&7) (inverse of store swizzle)
    const int jp      = l ^ ((l >> 3) & 7);
    const int laneoff = jp * W;

    const Ptrs P{ X + pb + laneoff, G1 + pb + laneoff,
                  G2 + pb + laneoff, G3 + pb + laneoff };
    float* out = O + pb + (size_t)(4 * l) * W;

    issue_half(P, lds4[0], 0);
    issue_half(P, lds4[1], 1);
    issue_half(P, lds4[2], 2);

    float h0 = 0.f, h1 = 0.f, h2 = 0.f, h3 = 0.f;
    float4 o[4][4];                      // [row r][sub-half]

#pragma unroll 1
    for (int p = 0; p < 16; ++p) {
        const int h = 4 * p;             // first of this group's 4 halves
        // Note p runs 0..15 over 64 halves?? NO: 64 halves? W/HC = 64 halves.
        // (see loop bound below)
        (void)h;
        break;
    }

    // W/HC = 64 half-tiles, grouped 4 per store round -> 16 rounds
#pragma unroll 1
    for (int p = 0; p < 16; ++p) {
        // ---- sub 0: h = 4p ----
        if (p == 0) WAITV(32); else WAITV(48);
        iter_body<0>(lds4[(4 * p) & 3], P, lds4[(4 * p + 3) & 3],
                     4 * p + 3, (4 * p + 3) < 64, l, lm, h0, h1, h2, h3, o);

        // ---- sub 1: h = 4p+1 ----
        if (p == 0) WAITV(32); else WAITV(48);
        iter_body<1>(lds4[(4 * p + 1) & 3], P, lds4[(4 * p + 4) & 3],
                     4 * p + 4, (4 * p + 4) < 64, l, lm, h0, h1, h2, h3, o);

        // ---- sub 2: h = 4p+2 ----
        if (p == 0) WAITV(32); else if (p == 15) WAITV(32); else WAITV(48);
        iter_body<2>(lds4[(4 * p + 2) & 3], P, lds4[(4 * p + 5) & 3],
                     4 * p + 5, (4 * p + 5) < 64, l, lm, h0, h1, h2, h3, o);

        // ---- sub 3: h = 4p+3 ----
        if (p == 15) WAITV(0); else WAITV(32);
        iter_body<3>(lds4[(4 * p + 3) & 3], P, lds4[(4 * p + 6) & 3],
                     4 * p + 6, (4 * p + 6) < 64, l, lm, h0, h1, h2, h3, o);

        // ---- store 16 cols x 4 rows (full 64B per row) ----
        const int wp = p * 16;
#pragma unroll
        for (int r = 0; r < 4; ++r) {
            float* po = out + r * W + wp;
            *reinterpret_cast<float4*>(po +  0) = o[r][0];
            *reinterpret_cast<float4*>(po +  4) = o[r][1];
            *reinterpret_cast<float4*>(po +  8) = o[r][2];
            *reinterpret_cast<float4*>(po + 12) = o[r][3];
        }
    }
}

extern "C" void kernel_launch(void* const* d_in, const int* in_sizes, int n_in,
                              void* d_out, int out_size, void* d_ws, size_t ws_size,
                              hipStream_t stream) {
    const float* X  = (const float*)d_in[0];
    const float* G1 = (const float*)d_in[1];
    const float* G2 = (const float*)d_in[2];
    const float* G3 = (const float*)d_in[3];
    float* O = (float*)d_out;

    const int planes = 8 * 64;   // 512 single-wave blocks, 2/CU, one round
    spn_wave<<<dim3(planes), dim3(64), 0, stream>>>(X, G1, G2, G3, O);
}

// Round 7
// 320.599 us; speedup vs baseline: 1.9116x; 1.9116x over previous
//
#include <hip/hip_runtime.h>

// GateRecurrent2dnoind: left-to-right SPN scan over W, 3-pt stencil along H.
// [N=8, C=64, H=256, W=256] fp32.
//
// R7: pure-register pipeline, NO LDS. One single-wave block per (n,c) plane
// (512 blocks, 2 waves/CU, one round). Lane l owns rows 4l..4l+3 -> vertical
// exchange = 2 intra-wave shuffles per step, zero barriers, zero LDS.
// Inputs loaded DIRECTLY to VGPRs: per 8-col tile, 4 arrays x 4 rows x 2
// float4 (s=0,1 back-to-back = 32B/row burst; pair tile one compute-phase
// later covers the other 32B of each 64B line -> R4's proven ideal-FETCH
// coverage profile). Double-buffered reg tiles A/B, counted vmcnt ledger:
// WAITV(32) x2 warm-up, WAITV(48) steady (next tile's 32 loads + 16 stores
// stay in flight, never drained), WAITV(0) only at the last tile.

constexpr int H  = 256;
constexpr int W  = 256;

#define F4C(v, j) ((&(v).x)[j])
#define WAITV(N) asm volatile("s_waitcnt vmcnt(" #N ")" ::: "memory")

struct Regs { float4 q[4][4][2]; };   // [array][row r][s] = 128 VGPRs

__device__ __forceinline__
void issue_tile(Regs& R,
                const float* __restrict__ b0, const float* __restrict__ b1,
                const float* __restrict__ b2, const float* __restrict__ b3,
                int w0)
{
#pragma unroll
    for (int r = 0; r < 4; ++r)
#pragma unroll
        for (int s = 0; s < 2; ++s) {
            const int off = r * W + w0 + 4 * s;   // imm-foldable (<4096B)
            R.q[0][r][s] = *reinterpret_cast<const float4*>(b0 + off);
            R.q[1][r][s] = *reinterpret_cast<const float4*>(b1 + off);
            R.q[2][r][s] = *reinterpret_cast<const float4*>(b2 + off);
            R.q[3][r][s] = *reinterpret_cast<const float4*>(b3 + off);
        }
}

// 8 sequential scan steps on one tile; outputs into o[.][OC0..OC0+1]
template<int OC0>
__device__ __forceinline__
void scan_tile(const Regs& R, int l,
               float& h0, float& h1, float& h2, float& h3, float4 o[4][4])
{
#pragma unroll
    for (int s = 0; s < 2; ++s)
#pragma unroll
        for (int j = 0; j < 4; ++j) {
            float up = __shfl_up(h3, 1);        // lane-1's row 4l-1
            float dn = __shfl_down(h0, 1);      // lane+1's row 4l+4
            if (l == 0)  up = 0.f;
            if (l == 63) dn = 0.f;

            const float x0 = F4C(R.q[0][0][s], j), a10 = F4C(R.q[1][0][s], j),
                        a20 = F4C(R.q[2][0][s], j), a30 = F4C(R.q[3][0][s], j);
            const float x1 = F4C(R.q[0][1][s], j), a11 = F4C(R.q[1][1][s], j),
                        a21 = F4C(R.q[2][1][s], j), a31 = F4C(R.q[3][1][s], j);
            const float x2 = F4C(R.q[0][2][s], j), a12 = F4C(R.q[1][2][s], j),
                        a22 = F4C(R.q[2][2][s], j), a32 = F4C(R.q[3][2][s], j);
            const float x3 = F4C(R.q[0][3][s], j), a13 = F4C(R.q[1][3][s], j),
                        a23 = F4C(R.q[2][3][s], j), a33 = F4C(R.q[3][3][s], j);

            const float n0 = fmaf(a30, h1, fmaf(a20, h0,
                             fmaf(a10, up, x0 * (1.f - a10 - a20 - a30))));
            const float n1 = fmaf(a31, h2, fmaf(a21, h1,
                             fmaf(a11, h0, x1 * (1.f - a11 - a21 - a31))));
            const float n2 = fmaf(a32, h3, fmaf(a22, h2,
                             fmaf(a12, h1, x2 * (1.f - a12 - a22 - a32))));
            const float n3 = fmaf(a33, dn, fmaf(a23, h3,
                             fmaf(a13, h2, x3 * (1.f - a13 - a23 - a33))));

            h0 = n0; h1 = n1; h2 = n2; h3 = n3;
            F4C(o[0][OC0 + s], j) = n0;
            F4C(o[1][OC0 + s], j) = n1;
            F4C(o[2][OC0 + s], j) = n2;
            F4C(o[3][OC0 + s], j) = n3;
        }
}

__global__ __launch_bounds__(64, 1)
void spn_regs(const float* __restrict__ X,  const float* __restrict__ G1,
              const float* __restrict__ G2, const float* __restrict__ G3,
              float* __restrict__ O)
{
    const int    l  = threadIdx.x;                      // 0..63
    const size_t pb = (size_t)blockIdx.x * (size_t)(H * W)
                    + (size_t)(4 * l) * W;              // lane's row base

    const float* b0 = X  + pb;
    const float* b1 = G1 + pb;
    const float* b2 = G2 + pb;
    const float* b3 = G3 + pb;
    float*       po = O  + pb;

    Regs A, B;
    issue_tile(A, b0, b1, b2, b3, 0);
    issue_tile(B, b0, b1, b2, b3, 8);

    float h0 = 0.f, h1 = 0.f, h2 = 0.f, h3 = 0.f;
    float4 o[4][4];                                     // [row r][col-group]

#pragma unroll 1
    for (int p = 0; p < 16; ++p) {
        // ---- even tile t = 2p (regs A) ----
        if (p == 0) WAITV(32); else WAITV(48);
        scan_tile<0>(A, l, h0, h1, h2, h3, o);
        if (p < 15) issue_tile(A, b0, b1, b2, b3, (2 * p + 2) * 8);

        // ---- odd tile t = 2p+1 (regs B) ----
        if (p == 0) WAITV(32); else if (p == 15) WAITV(0); else WAITV(48);
        scan_tile<2>(B, l, h0, h1, h2, h3, o);
        if (p < 15) issue_tile(B, b0, b1, b2, b3, (2 * p + 3) * 8);

        // ---- store 16 cols x 4 rows (full 64B per row) ----
        const int wp = p * 16;
#pragma unroll
        for (int r = 0; r < 4; ++r) {
            float* pr = po + r * W + wp;
            *reinterpret_cast<float4*>(pr +  0) = o[r][0];
            *reinterpret_cast<float4*>(pr +  4) = o[r][1];
            *reinterpret_cast<float4*>(pr +  8) = o[r][2];
            *reinterpret_cast<float4*>(pr + 12) = o[r][3];
        }
    }
}

extern "C" void kernel_launch(void* const* d_in, const int* in_sizes, int n_in,
                              void* d_out, int out_size, void* d_ws, size_t ws_size,
                              hipStream_t stream) {
    const float* X  = (const float*)d_in[0];
    const float* G1 = (const float*)d_in[1];
    const float* G2 = (const float*)d_in[2];
    const float* G3 = (const float*)d_in[3];
    float* O = (float*)d_out;

    const int planes = 8 * 64;   // 512 single-wave blocks, 2 waves/CU, one round
    spn_regs<<<dim3(planes), dim3(64), 0, stream>>>(X, G1, G2, G3, O);
}

// Round 8
// 281.646 us; speedup vs baseline: 2.1760x; 1.1383x over previous
//
#include <hip/hip_runtime.h>

// GateRecurrent2dnoind: left-to-right SPN scan over W, 3-pt stencil along H.
// [N=8, C=64, H=256, W=256] fp32.
//
// R8 = R1 structure (256-thread block per plane, thread t = row t, hbuf
// neighbor exchange, 1 barrier/step) + reg-staged DOUBLE BUFFERING:
//   - issue():  global->reg float4 loads for tile t+2 (32B/row per instr pair,
//               proven-ideal coalescing profile)
//   - stage():  reg->LDS ds_write for tile t+1 (2-way banks = free)
//   - preload per tile: all 32 scan operands LDS->reg before the step loop
//     (steps are then pub -> barrier -> 3 fmaf; no per-step ds_read latency)
// WT=8, PADW=9 -> sb = 73.7KB + hb 2KB -> 2 blocks/CU, all 512 blocks
// resident in ONE round; each block's barrier stalls are covered by the
// co-resident block's memory traffic. Outputs accumulate 16 cols in regs
// (static indexing only) -> 64B/row contiguous stores (proven-ideal writes).

constexpr int H    = 256;
constexpr int W    = 256;
constexpr int WT   = 8;
constexpr int NT   = W / WT;    // 32 tiles
constexpr int PADW = 9;         // odd stride -> 2-way (free) LDS banking

__global__ __launch_bounds__(256, 2)
void spn_block(const float* __restrict__ X,  const float* __restrict__ G1,
               const float* __restrict__ G2, const float* __restrict__ G3,
               float* __restrict__ O)
{
    __shared__ float sb[2][4][256 * PADW];  // [buf][array][row*PADW+col] 73.7KB
    __shared__ float hb[2][258];            // zero-padded ends

    const int    t  = threadIdx.x;          // row index 0..255
    const size_t pb = (size_t)blockIdx.x * (size_t)(H * W);
    const float* __restrict__ a0 = X  + pb;
    const float* __restrict__ a1 = G1 + pb;
    const float* __restrict__ a2 = G2 + pb;
    const float* __restrict__ a3 = G3 + pb;

    // staging mapping: 2 passes; pass p covers rows p*128 + (t>>1),
    // lanes 2k,2k+1 cover 32B contiguous per row per instruction pair.
    const int srow = t >> 1, scol = (t & 1) << 2;
    float4 rg[4][2];                        // [array][pass]

    auto issue = [&](int tile) {
        const int w0 = tile * WT + scol;
#pragma unroll
        for (int p = 0; p < 2; ++p) {
            const size_t off = (size_t)(p * 128 + srow) * W + w0;
            rg[0][p] = *reinterpret_cast<const float4*>(a0 + off);
            rg[1][p] = *reinterpret_cast<const float4*>(a1 + off);
            rg[2][p] = *reinterpret_cast<const float4*>(a2 + off);
            rg[3][p] = *reinterpret_cast<const float4*>(a3 + off);
        }
    };
    auto stage = [&](int b) {
#pragma unroll
        for (int p = 0; p < 2; ++p) {
            const int l = (p * 128 + srow) * PADW + scol;
#pragma unroll
            for (int a = 0; a < 4; ++a) {
                sb[b][a][l + 0] = (&rg[a][p].x)[0];
                sb[b][a][l + 1] = (&rg[a][p].x)[1];
                sb[b][a][l + 2] = (&rg[a][p].x)[2];
                sb[b][a][l + 3] = (&rg[a][p].x)[3];
            }
        }
    };

    if (t < 2) { hb[0][t * 257] = 0.f; hb[1][t * 257] = 0.f; }  // [0], [257]

    issue(0); stage(0);          // prologue: tile0 -> sb[0]
    issue(1);                    // tile1 staged at end of tile0
    __syncthreads();

    float h = 0.f;
    const int lrow = t * PADW;

    // one tile: preload operands -> 8 scan steps -> stage(t+1) -> issue(t+2)
    auto do_tile = [&](int tile, float (&o8)[8]) {
        const float* __restrict__ xb = sb[tile & 1][0];
        const float* __restrict__ b1 = sb[tile & 1][1];
        const float* __restrict__ b2 = sb[tile & 1][2];
        const float* __restrict__ b3 = sb[tile & 1][3];

        float qx[8], q1[8], q2[8], q3[8];
#pragma unroll
        for (int ww = 0; ww < 8; ++ww) {
            qx[ww] = xb[lrow + ww]; q1[ww] = b1[lrow + ww];
            q2[ww] = b2[lrow + ww]; q3[ww] = b3[lrow + ww];
        }
#pragma unroll
        for (int ww = 0; ww < 8; ++ww) {
            float* hp = hb[ww & 1];
            hp[t + 1] = h;                    // publish h_prev
            __syncthreads();
            const float hu = hp[t], hd = hp[t + 2];
            h = fmaf(q3[ww], hd, fmaf(q2[ww], h, fmaf(q1[ww], hu,
                     qx[ww] * (1.f - q1[ww] - q2[ww] - q3[ww]))));
            o8[ww] = h;
        }
        // sb[(tile+1)&1]'s last readers finished at tile-1 (barrier'd) -> safe
        if (tile + 1 < NT) stage((tile + 1) & 1);
        if (tile + 2 < NT) issue(tile + 2);
        __syncthreads();                      // staged data visible to next tile
    };

    float* __restrict__ orow = O + pb + (size_t)t * W;

#pragma unroll 1
    for (int p = 0; p < NT / 2; ++p) {
        float oA[8], oB[8];
        do_tile(2 * p,     oA);
        do_tile(2 * p + 1, oB);
        // 16 accumulated cols -> 4 contiguous float4 = full 64B per row
        float* po = orow + p * 16;
        *reinterpret_cast<float4*>(po +  0) = make_float4(oA[0], oA[1], oA[2], oA[3]);
        *reinterpret_cast<float4*>(po +  4) = make_float4(oA[4], oA[5], oA[6], oA[7]);
        *reinterpret_cast<float4*>(po +  8) = make_float4(oB[0], oB[1], oB[2], oB[3]);
        *reinterpret_cast<float4*>(po + 12) = make_float4(oB[4], oB[5], oB[6], oB[7]);
    }
}

extern "C" void kernel_launch(void* const* d_in, const int* in_sizes, int n_in,
                              void* d_out, int out_size, void* d_ws, size_t ws_size,
                              hipStream_t stream) {
    const float* X  = (const float*)d_in[0];
    const float* G1 = (const float*)d_in[1];
    const float* G2 = (const float*)d_in[2];
    const float* G3 = (const float*)d_in[3];
    float* O = (float*)d_out;

    const int planes = 8 * 64;   // 512 blocks, 2 per CU, one resident round
    spn_block<<<dim3(planes), dim3(256), 0, stream>>>(X, G1, G2, G3, O);
}